// Round 13
// baseline (102.838 us; speedup 1.0000x reference)
//
#include <hip/hip_runtime.h>
#include <hip/hip_bf16.h>
#include <stdint.h>

// LinearEnsemble: out[b,m,o] = sum_i W[m,o,i]*x[b,i] + bias[m,o]
// == C[4096x8192] = x[4096x1024] * Wbig^T (+bias), Wbig = [8192x1024] row-major.
// v14 (FINAL): revert to v10 (best measured, 90.0us total) + non-temporal
//   epilogue stores (output is write-once; keep it out of L2 so A/B panels
//   survive -> FETCH_SIZE 49MB vs 24MB compulsory suggests write-evictions).
//   Structure (verified across 12 rounds):
//   - 256x256 tile, 8 waves, ring-4 K=32 slices, staging 3 ahead via
//     global_load_lds w16, counted VMCNT(8) guard (taper 8->4->0), 1 barrier/slice.
//   - granule involution swizzle (SQ_LDS_BANK_CONFLICT == 0 measured).
//   - counted-lgkm ladder: each MFMA quad waits only its own A-frag.
//   - separate vectorized f32->bf16 cvt pass (fusing it regressed: v11).
//   Plateau note: MfmaUtil ~31%, HBM ~28% -- neither saturated; 8 schedule
//   variants (incl. faithful m201 ports) all landed 90-96us. Composition:
//   ~12us cvt (BW floor) + ~57us K-loop + ~21us epilogue write (BW).

typedef __bf16 bf16;
typedef __attribute__((ext_vector_type(8))) __bf16 bf16x8;
typedef __attribute__((ext_vector_type(4))) float f32x4;

#define GAS __attribute__((address_space(1)))
#define LAS __attribute__((address_space(3)))

__device__ __forceinline__ void gload_lds16(void* lds, const void* g) {
    __builtin_amdgcn_global_load_lds((const GAS uint32_t*)g, (LAS uint32_t*)lds, 16, 0, 0);
}

// raw barrier with compiler-level memory fence (no vmcnt/lgkm drain emitted)
__device__ __forceinline__ void wg_barrier() {
    asm volatile("" ::: "memory");
    __builtin_amdgcn_s_barrier();
    asm volatile("" ::: "memory");
}

#define VMCNT(n)   asm volatile("s_waitcnt vmcnt(" #n ")" ::: "memory")
#define LGKMCNT(n) asm volatile("s_waitcnt lgkmcnt(" #n ")" ::: "memory")
#define SCHED_FENCE() __builtin_amdgcn_sched_barrier(0)

// untracked LDS fragment read; ordering enforced by counted waits + SCHED_FENCE
template<int OFF>
__device__ __forceinline__ bf16x8 ds_read_frag(const char* p) {
    f32x4 r;
    asm volatile("ds_read_b128 %0, %1 offset:%2"
                 : "=v"(r)
                 : "v"((const LAS char*)p), "i"(OFF));
    return __builtin_bit_cast(bf16x8, r);
}

__device__ __forceinline__ uint4 pack8(float4 a, float4 b) {
    union { bf16 t[8]; uint4 v; } u;
    u.t[0] = (bf16)a.x; u.t[1] = (bf16)a.y; u.t[2] = (bf16)a.z; u.t[3] = (bf16)a.w;
    u.t[4] = (bf16)b.x; u.t[5] = (bf16)b.y; u.t[6] = (bf16)b.z; u.t[7] = (bf16)b.w;
    return u.v;
}

// ---------------- fused f32 -> bf16 convert for x and W (one launch) ----------------
__global__ void LE_cvt2_kernel(const float* __restrict__ x, const float* __restrict__ w,
                               bf16* __restrict__ out, int nx, int ntot) {
    const int stride = gridDim.x * blockDim.x * 8;
    for (int i = (blockIdx.x * blockDim.x + threadIdx.x) * 8; i < ntot; i += stride) {
        const float* s = (i < nx) ? (x + i) : (w + (i - nx));
        float4 f0 = *(const float4*)s;
        float4 f1 = *(const float4*)(s + 4);
        *(uint4*)(out + i) = pack8(f0, f1);
    }
}

// ---------------- 256x256 deep-pipelined MFMA GEMM ----------------
// 512 threads = 8 waves (2 row x 4 col), wave owns 128x64 of C (8x4 frags of 16x16).
// LDS: ring of 4 K=32 slices, each = A[256][32] + B[256][32] bf16 = 32 KB -> 128 KiB.
// Granule swizzle: source granule (t&3)^((t>>3)&3), read granule fq^((fr>>1)&3).
// Staging 3 slices ahead; guard VMCNT(8) once per slice (taper 8->4->0).
__global__ __launch_bounds__(512, 2) void LE_gemm8_kernel(const bf16* __restrict__ A,
                                                          const bf16* __restrict__ B,
                                                          const float* __restrict__ bias,
                                                          float* __restrict__ out) {
    constexpr int K  = 1024;
    constexpr int NS = 32;                 // K / 32 slices
    __shared__ bf16 As[4][256 * 32];       // 64 KB (slot stride 16384 B)
    __shared__ bf16 Bs[4][256 * 32];       // 64 KB

    // XCD band swizzle: 512 blocks, each XCD gets 16 row-tiles x 4 col-tiles.
    const int raw  = blockIdx.x;
    const int xcd  = raw & 7;
    const int idx  = raw >> 3;             // 0..63
    const int trow = idx >> 2;             // 0..15
    const int tcol = xcd * 4 + (idx & 3);  // 0..31

    const int tid  = threadIdx.x;
    const int lane = tid & 63;
    const int w    = tid >> 6;             // wave 0..7
    const int wr   = w >> 2, wc = w & 3;   // 2 x 4 wave grid
    const int fr   = lane & 15;
    const int fq   = lane >> 4;

    const bf16* Ag = A + (size_t)trow * 256 * K;
    const bf16* Bg = B + (size_t)tcol * 256 * K;
    // staging: thread t covers 16 B of row (t>>2) [+128 for 2nd issue].
    // Source granule pre-swizzled so the linear LDS write realizes the XOR layout.
    const int sgran = ((tid & 3) ^ ((tid >> 3) & 3)) * 8;
    const bf16* a_src = Ag + (size_t)(tid >> 2) * K + sgran;
    const bf16* b_src = Bg + (size_t)(tid >> 2) * K + sgran;

    // fragment-read bases (byte offsets within a slot), same XOR on granule
    const int rgran = (fq ^ ((fr >> 1) & 3)) * 8;
    const int aoff_b = ((wr * 128 + fr) * 32 + rgran) * 2;  // + mi*1024 imm, +4096 m-half1
    const int boff_b = ((wc * 64  + fr) * 32 + rgran) * 2;  // + ni*1024 imm

    f32x4 acc[8][4];
    const f32x4 zero = {0.f, 0.f, 0.f, 0.f};
#pragma unroll
    for (int mi = 0; mi < 8; ++mi)
#pragma unroll
        for (int ni = 0; ni < 4; ++ni) acc[mi][ni] = zero;

    // -------- prologue: stage slices 0,1,2 (12 loads/thread), land slice 0 --------
    for (int js = 0; js < 3; ++js) {
        char* da = (char*)As + js * 16384 + tid * 16;
        char* db = (char*)Bs + js * 16384 + tid * 16;
        const bf16* sa = a_src + js * 32;
        const bf16* sb = b_src + js * 32;
        gload_lds16(da,        sa);
        gload_lds16(da + 8192, sa + (size_t)128 * K);
        gload_lds16(db,        sb);
        gload_lds16(db + 8192, sb + (size_t)128 * K);
    }
    VMCNT(8);          // drain slice 0 (slices 1,2 stay in flight)
    wg_barrier();

#define MFMA_QUAD(MI, AV)                                                              \
    acc[MI][0] = __builtin_amdgcn_mfma_f32_16x16x32_bf16(AV, bv0, acc[MI][0], 0, 0, 0); \
    acc[MI][1] = __builtin_amdgcn_mfma_f32_16x16x32_bf16(AV, bv1, acc[MI][1], 0, 0, 0); \
    acc[MI][2] = __builtin_amdgcn_mfma_f32_16x16x32_bf16(AV, bv2, acc[MI][2], 0, 0, 0); \
    acc[MI][3] = __builtin_amdgcn_mfma_f32_16x16x32_bf16(AV, bv3, acc[MI][3], 0, 0, 0)

    for (int jo = 0; jo < NS; jo += 4) {
#pragma unroll
        for (int s = 0; s < 4; ++s) {
            const int j = jo + s;
            const char* pa = (const char*)As + s * 16384 + aoff_b;
            const char* pb = (const char*)Bs + s * 16384 + boff_b;

            // front: B frags then m-half0 A frags (order matters for the counted
            // lgkm ladder: oldest 5 = bv0..3 + af0)
            bf16x8 bv0 = ds_read_frag<0>(pb);
            bf16x8 bv1 = ds_read_frag<1024>(pb);
            bf16x8 bv2 = ds_read_frag<2048>(pb);
            bf16x8 bv3 = ds_read_frag<3072>(pb);
            bf16x8 af0 = ds_read_frag<0>(pa);
            bf16x8 af1 = ds_read_frag<1024>(pa);
            bf16x8 af2 = ds_read_frag<2048>(pa);
            bf16x8 af3 = ds_read_frag<3072>(pa);
            if (j < NS - 3) {              // stage slice j+3 (vmcnt-only; doesn't
                const int ns = (j + 3) & 3;//  perturb the lgkm ladder)
                char* da = (char*)As + ns * 16384 + tid * 16;
                char* db = (char*)Bs + ns * 16384 + tid * 16;
                const bf16* sa = a_src + (j + 3) * 32;
                const bf16* sb = b_src + (j + 3) * 32;
                gload_lds16(da,        sa);
                gload_lds16(da + 8192, sa + (size_t)128 * K);
                gload_lds16(db,        sb);
                gload_lds16(db + 8192, sb + (size_t)128 * K);
            }

            // counted-lgkm ladder: each quad waits exactly for its own A-frag;
            // m-half1 reads issue one quad ahead of use. DS retires in-order.
            bf16x8 ag0, ag1, ag2, ag3;
            LGKMCNT(3); SCHED_FENCE();     // bv0..3 + af0 landed (af1..3 out)
            MFMA_QUAD(0, af0); ag0 = ds_read_frag<4096 + 0>(pa);
            LGKMCNT(3); SCHED_FENCE();     // af1 landed (af2,af3,ag0 out)
            MFMA_QUAD(1, af1); ag1 = ds_read_frag<4096 + 1024>(pa);
            LGKMCNT(3); SCHED_FENCE();     // af2 landed (af3,ag0,ag1 out)
            MFMA_QUAD(2, af2); ag2 = ds_read_frag<4096 + 2048>(pa);
            LGKMCNT(3); SCHED_FENCE();     // af3 landed (ag0,ag1,ag2 out)
            MFMA_QUAD(3, af3); ag3 = ds_read_frag<4096 + 3072>(pa);
            LGKMCNT(3); SCHED_FENCE();     // ag0 landed (ag1,ag2,ag3 out)
            MFMA_QUAD(4, ag0);
            LGKMCNT(2); SCHED_FENCE();     // ag1 landed
            MFMA_QUAD(5, ag1);
            LGKMCNT(1); SCHED_FENCE();     // ag2 landed
            MFMA_QUAD(6, ag2);
            LGKMCNT(0); SCHED_FENCE();     // ag3 landed
            MFMA_QUAD(7, ag3);

            // single slice-end sync point: per-wave counted guard for slot j+1,
            // barrier globalizes it AND licenses staging into slot (j+4)&3.
            if (j <= NS - 4)      { VMCNT(8); wg_barrier(); }
            else if (j == NS - 3) { VMCNT(4); wg_barrier(); }
            else if (j == NS - 2) { VMCNT(0); wg_barrier(); }
            // j == NS-1: last slice, fall through to epilogue
        }
    }
#undef MFMA_QUAD

    // ---------------- epilogue: C = acc + bias[col], non-temporal stores ----------------
    // Output is write-once; nt stores keep the 134 MB stream out of L2 so the
    // A/B panels (and other blocks' staging) survive there.
    const int rowb = trow * 256 + wr * 128;
    const int colb = tcol * 256 + wc * 64;
    float bv[4];
#pragma unroll
    for (int fn = 0; fn < 4; ++fn) bv[fn] = bias[colb + fn * 16 + fr];
#pragma unroll
    for (int fm = 0; fm < 8; ++fm) {
        const int r0 = rowb + fm * 16 + fq * 4;
#pragma unroll
        for (int fn = 0; fn < 4; ++fn) {
            const int c = colb + fn * 16 + fr;
            float* p = out + (size_t)r0 * 8192 + c;
            f32x4 v = acc[fm][fn];
            __builtin_nontemporal_store(v[0] + bv[fn], p + 0 * 8192);
            __builtin_nontemporal_store(v[1] + bv[fn], p + 1 * 8192);
            __builtin_nontemporal_store(v[2] + bv[fn], p + 2 * 8192);
            __builtin_nontemporal_store(v[3] + bv[fn], p + 3 * 8192);
        }
    }
}

// ---------------- fallback (no workspace): reg-staged f32 128x128 GEMM ----------------
__global__ __launch_bounds__(256) void LE_gemm_fb_kernel(const float* __restrict__ A,
                                                         const float* __restrict__ B,
                                                         const float* __restrict__ bias,
                                                         float* __restrict__ out) {
    constexpr int K = 1024;
    __shared__ bf16 As[128 * 32];
    __shared__ bf16 Bs[128 * 32];

    const int raw  = blockIdx.x;
    const int xcd  = raw & 7;
    const int idx  = raw >> 3;
    const int trow = idx & 31;
    const int tcol = xcd * 8 + (idx >> 5);

    const int tid  = threadIdx.x;
    const int lane = tid & 63;
    const int w    = tid >> 6;
    const int wr   = w >> 1, wc = w & 1;
    const int fr   = lane & 15;
    const int fq   = lane >> 4;

    f32x4 acc[4][4];
    const f32x4 zero = {0.f, 0.f, 0.f, 0.f};
#pragma unroll
    for (int mi = 0; mi < 4; mi++)
#pragma unroll
        for (int ni = 0; ni < 4; ni++) acc[mi][ni] = zero;

    const float* Ap = A + (size_t)trow * 128 * K;
    const float* Bp = B + (size_t)tcol * 128 * K;
    const int sr = tid >> 1;
    const int sc = (tid & 1) * 16;
    for (int k0 = 0; k0 < K; k0 += 32) {
        const float* pa = Ap + (size_t)sr * K + k0 + sc;
        const float* pb = Bp + (size_t)sr * K + k0 + sc;
        float4 a0 = *(const float4*)(pa + 0);
        float4 a1 = *(const float4*)(pa + 4);
        float4 a2 = *(const float4*)(pa + 8);
        float4 a3 = *(const float4*)(pa + 12);
        float4 b0 = *(const float4*)(pb + 0);
        float4 b1 = *(const float4*)(pb + 4);
        float4 b2 = *(const float4*)(pb + 8);
        float4 b3 = *(const float4*)(pb + 12);
        __syncthreads();
        char* la = (char*)As + sr * 64 + sc * 2;
        char* lb = (char*)Bs + sr * 64 + sc * 2;
        *(uint4*)(la)      = pack8(a0, a1);
        *(uint4*)(la + 16) = pack8(a2, a3);
        *(uint4*)(lb)      = pack8(b0, b1);
        *(uint4*)(lb + 16) = pack8(b2, b3);
        __syncthreads();
        bf16x8 af[4], bfv2[4];
#pragma unroll
        for (int mi = 0; mi < 4; mi++)
            af[mi] = *(const bf16x8*)&As[(wr * 64 + mi * 16 + fr) * 32 + fq * 8];
#pragma unroll
        for (int ni = 0; ni < 4; ni++)
            bfv2[ni] = *(const bf16x8*)&Bs[(wc * 64 + ni * 16 + fr) * 32 + fq * 8];
#pragma unroll
        for (int mi = 0; mi < 4; mi++)
#pragma unroll
            for (int ni = 0; ni < 4; ni++)
                acc[mi][ni] = __builtin_amdgcn_mfma_f32_16x16x32_bf16(af[mi], bfv2[ni],
                                                                      acc[mi][ni], 0, 0, 0);
    }
    __syncthreads();

    const int rowb = trow * 128 + wr * 64;
    const int colb = tcol * 128 + wc * 64;
#pragma unroll
    for (int mi = 0; mi < 4; mi++) {
        const int r0 = rowb + mi * 16 + fq * 4;
#pragma unroll
        for (int ni = 0; ni < 4; ni++) {
            const int c = colb + ni * 16 + fr;
            const float bvv = bias[c];
            float* p = out + (size_t)r0 * 8192 + c;
            f32x4 v = acc[mi][ni];
            p[0 * 8192] = v[0] + bvv;
            p[1 * 8192] = v[1] + bvv;
            p[2 * 8192] = v[2] + bvv;
            p[3 * 8192] = v[3] + bvv;
        }
    }
}

extern "C" void kernel_launch(void* const* d_in, const int* in_sizes, int n_in,
                              void* d_out, int out_size, void* d_ws, size_t ws_size,
                              hipStream_t stream) {
    const float* x    = (const float*)d_in[0];   // [4096, 1024]
    const float* wgt  = (const float*)d_in[1];   // [8, 1024, 1024] == Wbig^T [8192,1024]
    const float* bias = (const float*)d_in[2];   // [8, 1024] == [8192]
    float* out = (float*)d_out;                  // [4096, 8192]

    const size_t NX = (size_t)4096 * 1024;
    const size_t NW = (size_t)8192 * 1024;

    if (ws_size >= (NX + NW) * sizeof(bf16)) {
        bf16* xb = (bf16*)d_ws;
        bf16* wb = xb + NX;
        LE_cvt2_kernel<<<2048, 256, 0, stream>>>(x, wgt, xb, (int)NX, (int)(NX + NW));
        LE_gemm8_kernel<<<512, 512, 0, stream>>>(xb, wb, bias, out);
    } else {
        LE_gemm_fb_kernel<<<2048, 256, 0, stream>>>(x, wgt, bias, out);
    }
}

// Round 14
// 89.572 us; speedup vs baseline: 1.1481x; 1.1481x over previous
//
#include <hip/hip_runtime.h>
#include <hip/hip_bf16.h>
#include <stdint.h>

// LinearEnsemble: out[b,m,o] = sum_i W[m,o,i]*x[b,i] + bias[m,o]
// == C[4096x8192] = x[4096x1024] * Wbig^T (+bias), Wbig = [8192x1024] row-major.
// v15 (FINAL = v10 exact revert; best measured 90.0us total).
//   v14's non-temporal epilogue stores regressed (102.8us) and falsified the
//   L2-write-eviction theory (FETCH_SIZE unchanged at 49MB): plain stores
//   restored. Session-verified structure:
//   - separate vectorized f32->bf16 cvt pass (fusing regressed, v11)
//   - 256x256 tile, 8 waves, ring-4 K=32 slices, staging 3 ahead via
//     global_load_lds w16, counted VMCNT(8) guard (taper 8->4->0), 1 bar/slice
//   - granule involution swizzle (SQ_LDS_BANK_CONFLICT == 0 measured)
//   - counted-lgkm ladder: each MFMA quad waits only its own A-frag
//   - XCD band swizzle (FETCH 107->49 MB vs 128-tile baseline)
//   Plateau, not roofline: MfmaUtil ~32%, HBM ~28% -- 8 schedule variants
//   (incl. faithful m201 8-phase ports) all landed 90-96us.

typedef __bf16 bf16;
typedef __attribute__((ext_vector_type(8))) __bf16 bf16x8;
typedef __attribute__((ext_vector_type(4))) float f32x4;

#define GAS __attribute__((address_space(1)))
#define LAS __attribute__((address_space(3)))

__device__ __forceinline__ void gload_lds16(void* lds, const void* g) {
    __builtin_amdgcn_global_load_lds((const GAS uint32_t*)g, (LAS uint32_t*)lds, 16, 0, 0);
}

// raw barrier with compiler-level memory fence (no vmcnt/lgkm drain emitted)
__device__ __forceinline__ void wg_barrier() {
    asm volatile("" ::: "memory");
    __builtin_amdgcn_s_barrier();
    asm volatile("" ::: "memory");
}

#define VMCNT(n)   asm volatile("s_waitcnt vmcnt(" #n ")" ::: "memory")
#define LGKMCNT(n) asm volatile("s_waitcnt lgkmcnt(" #n ")" ::: "memory")
#define SCHED_FENCE() __builtin_amdgcn_sched_barrier(0)

// untracked LDS fragment read; ordering enforced by counted waits + SCHED_FENCE
template<int OFF>
__device__ __forceinline__ bf16x8 ds_read_frag(const char* p) {
    f32x4 r;
    asm volatile("ds_read_b128 %0, %1 offset:%2"
                 : "=v"(r)
                 : "v"((const LAS char*)p), "i"(OFF));
    return __builtin_bit_cast(bf16x8, r);
}

__device__ __forceinline__ uint4 pack8(float4 a, float4 b) {
    union { bf16 t[8]; uint4 v; } u;
    u.t[0] = (bf16)a.x; u.t[1] = (bf16)a.y; u.t[2] = (bf16)a.z; u.t[3] = (bf16)a.w;
    u.t[4] = (bf16)b.x; u.t[5] = (bf16)b.y; u.t[6] = (bf16)b.z; u.t[7] = (bf16)b.w;
    return u.v;
}

// ---------------- fused f32 -> bf16 convert for x and W (one launch) ----------------
__global__ void LE_cvt2_kernel(const float* __restrict__ x, const float* __restrict__ w,
                               bf16* __restrict__ out, int nx, int ntot) {
    const int stride = gridDim.x * blockDim.x * 8;
    for (int i = (blockIdx.x * blockDim.x + threadIdx.x) * 8; i < ntot; i += stride) {
        const float* s = (i < nx) ? (x + i) : (w + (i - nx));
        float4 f0 = *(const float4*)s;
        float4 f1 = *(const float4*)(s + 4);
        *(uint4*)(out + i) = pack8(f0, f1);
    }
}

// ---------------- 256x256 deep-pipelined MFMA GEMM ----------------
// 512 threads = 8 waves (2 row x 4 col), wave owns 128x64 of C (8x4 frags of 16x16).
// LDS: ring of 4 K=32 slices, each = A[256][32] + B[256][32] bf16 = 32 KB -> 128 KiB.
// Granule swizzle: source granule (t&3)^((t>>3)&3), read granule fq^((fr>>1)&3).
// Staging 3 slices ahead; guard VMCNT(8) once per slice (taper 8->4->0).
__global__ __launch_bounds__(512, 2) void LE_gemm8_kernel(const bf16* __restrict__ A,
                                                          const bf16* __restrict__ B,
                                                          const float* __restrict__ bias,
                                                          float* __restrict__ out) {
    constexpr int K  = 1024;
    constexpr int NS = 32;                 // K / 32 slices
    __shared__ bf16 As[4][256 * 32];       // 64 KB (slot stride 16384 B)
    __shared__ bf16 Bs[4][256 * 32];       // 64 KB

    // XCD band swizzle: 512 blocks, each XCD gets 16 row-tiles x 4 col-tiles.
    const int raw  = blockIdx.x;
    const int xcd  = raw & 7;
    const int idx  = raw >> 3;             // 0..63
    const int trow = idx >> 2;             // 0..15
    const int tcol = xcd * 4 + (idx & 3);  // 0..31

    const int tid  = threadIdx.x;
    const int lane = tid & 63;
    const int w    = tid >> 6;             // wave 0..7
    const int wr   = w >> 2, wc = w & 3;   // 2 x 4 wave grid
    const int fr   = lane & 15;
    const int fq   = lane >> 4;

    const bf16* Ag = A + (size_t)trow * 256 * K;
    const bf16* Bg = B + (size_t)tcol * 256 * K;
    // staging: thread t covers 16 B of row (t>>2) [+128 for 2nd issue].
    // Source granule pre-swizzled so the linear LDS write realizes the XOR layout.
    const int sgran = ((tid & 3) ^ ((tid >> 3) & 3)) * 8;
    const bf16* a_src = Ag + (size_t)(tid >> 2) * K + sgran;
    const bf16* b_src = Bg + (size_t)(tid >> 2) * K + sgran;

    // fragment-read bases (byte offsets within a slot), same XOR on granule
    const int rgran = (fq ^ ((fr >> 1) & 3)) * 8;
    const int aoff_b = ((wr * 128 + fr) * 32 + rgran) * 2;  // + mi*1024 imm, +4096 m-half1
    const int boff_b = ((wc * 64  + fr) * 32 + rgran) * 2;  // + ni*1024 imm

    f32x4 acc[8][4];
    const f32x4 zero = {0.f, 0.f, 0.f, 0.f};
#pragma unroll
    for (int mi = 0; mi < 8; ++mi)
#pragma unroll
        for (int ni = 0; ni < 4; ++ni) acc[mi][ni] = zero;

    // -------- prologue: stage slices 0,1,2 (12 loads/thread), land slice 0 --------
    for (int js = 0; js < 3; ++js) {
        char* da = (char*)As + js * 16384 + tid * 16;
        char* db = (char*)Bs + js * 16384 + tid * 16;
        const bf16* sa = a_src + js * 32;
        const bf16* sb = b_src + js * 32;
        gload_lds16(da,        sa);
        gload_lds16(da + 8192, sa + (size_t)128 * K);
        gload_lds16(db,        sb);
        gload_lds16(db + 8192, sb + (size_t)128 * K);
    }
    VMCNT(8);          // drain slice 0 (slices 1,2 stay in flight)
    wg_barrier();

#define MFMA_QUAD(MI, AV)                                                              \
    acc[MI][0] = __builtin_amdgcn_mfma_f32_16x16x32_bf16(AV, bv0, acc[MI][0], 0, 0, 0); \
    acc[MI][1] = __builtin_amdgcn_mfma_f32_16x16x32_bf16(AV, bv1, acc[MI][1], 0, 0, 0); \
    acc[MI][2] = __builtin_amdgcn_mfma_f32_16x16x32_bf16(AV, bv2, acc[MI][2], 0, 0, 0); \
    acc[MI][3] = __builtin_amdgcn_mfma_f32_16x16x32_bf16(AV, bv3, acc[MI][3], 0, 0, 0)

    for (int jo = 0; jo < NS; jo += 4) {
#pragma unroll
        for (int s = 0; s < 4; ++s) {
            const int j = jo + s;
            const char* pa = (const char*)As + s * 16384 + aoff_b;
            const char* pb = (const char*)Bs + s * 16384 + boff_b;

            // front: B frags then m-half0 A frags (order matters for the counted
            // lgkm ladder: oldest 5 = bv0..3 + af0)
            bf16x8 bv0 = ds_read_frag<0>(pb);
            bf16x8 bv1 = ds_read_frag<1024>(pb);
            bf16x8 bv2 = ds_read_frag<2048>(pb);
            bf16x8 bv3 = ds_read_frag<3072>(pb);
            bf16x8 af0 = ds_read_frag<0>(pa);
            bf16x8 af1 = ds_read_frag<1024>(pa);
            bf16x8 af2 = ds_read_frag<2048>(pa);
            bf16x8 af3 = ds_read_frag<3072>(pa);
            if (j < NS - 3) {              // stage slice j+3 (vmcnt-only; doesn't
                const int ns = (j + 3) & 3;//  perturb the lgkm ladder)
                char* da = (char*)As + ns * 16384 + tid * 16;
                char* db = (char*)Bs + ns * 16384 + tid * 16;
                const bf16* sa = a_src + (j + 3) * 32;
                const bf16* sb = b_src + (j + 3) * 32;
                gload_lds16(da,        sa);
                gload_lds16(da + 8192, sa + (size_t)128 * K);
                gload_lds16(db,        sb);
                gload_lds16(db + 8192, sb + (size_t)128 * K);
            }

            // counted-lgkm ladder: each quad waits exactly for its own A-frag;
            // m-half1 reads issue one quad ahead of use. DS retires in-order.
            bf16x8 ag0, ag1, ag2, ag3;
            LGKMCNT(3); SCHED_FENCE();     // bv0..3 + af0 landed (af1..3 out)
            MFMA_QUAD(0, af0); ag0 = ds_read_frag<4096 + 0>(pa);
            LGKMCNT(3); SCHED_FENCE();     // af1 landed (af2,af3,ag0 out)
            MFMA_QUAD(1, af1); ag1 = ds_read_frag<4096 + 1024>(pa);
            LGKMCNT(3); SCHED_FENCE();     // af2 landed (af3,ag0,ag1 out)
            MFMA_QUAD(2, af2); ag2 = ds_read_frag<4096 + 2048>(pa);
            LGKMCNT(3); SCHED_FENCE();     // af3 landed (ag0,ag1,ag2 out)
            MFMA_QUAD(3, af3); ag3 = ds_read_frag<4096 + 3072>(pa);
            LGKMCNT(3); SCHED_FENCE();     // ag0 landed (ag1,ag2,ag3 out)
            MFMA_QUAD(4, ag0);
            LGKMCNT(2); SCHED_FENCE();     // ag1 landed
            MFMA_QUAD(5, ag1);
            LGKMCNT(1); SCHED_FENCE();     // ag2 landed
            MFMA_QUAD(6, ag2);
            LGKMCNT(0); SCHED_FENCE();     // ag3 landed
            MFMA_QUAD(7, ag3);

            // single slice-end sync point: per-wave counted guard for slot j+1,
            // barrier globalizes it AND licenses staging into slot (j+4)&3.
            if (j <= NS - 4)      { VMCNT(8); wg_barrier(); }
            else if (j == NS - 3) { VMCNT(4); wg_barrier(); }
            else if (j == NS - 2) { VMCNT(0); wg_barrier(); }
            // j == NS-1: last slice, fall through to epilogue
        }
    }
#undef MFMA_QUAD

    // ---------------- epilogue: C = acc + bias[col] ----------------
    const int rowb = trow * 256 + wr * 128;
    const int colb = tcol * 256 + wc * 64;
    float bv[4];
#pragma unroll
    for (int fn = 0; fn < 4; ++fn) bv[fn] = bias[colb + fn * 16 + fr];
#pragma unroll
    for (int fm = 0; fm < 8; ++fm) {
        const int r0 = rowb + fm * 16 + fq * 4;
#pragma unroll
        for (int fn = 0; fn < 4; ++fn) {
            const int c = colb + fn * 16 + fr;
            float* p = out + (size_t)r0 * 8192 + c;
            f32x4 v = acc[fm][fn];
            p[0 * 8192] = v[0] + bv[fn];
            p[1 * 8192] = v[1] + bv[fn];
            p[2 * 8192] = v[2] + bv[fn];
            p[3 * 8192] = v[3] + bv[fn];
        }
    }
}

// ---------------- fallback (no workspace): reg-staged f32 128x128 GEMM ----------------
__global__ __launch_bounds__(256) void LE_gemm_fb_kernel(const float* __restrict__ A,
                                                         const float* __restrict__ B,
                                                         const float* __restrict__ bias,
                                                         float* __restrict__ out) {
    constexpr int K = 1024;
    __shared__ bf16 As[128 * 32];
    __shared__ bf16 Bs[128 * 32];

    const int raw  = blockIdx.x;
    const int xcd  = raw & 7;
    const int idx  = raw >> 3;
    const int trow = idx & 31;
    const int tcol = xcd * 8 + (idx >> 5);

    const int tid  = threadIdx.x;
    const int lane = tid & 63;
    const int w    = tid >> 6;
    const int wr   = w >> 1, wc = w & 1;
    const int fr   = lane & 15;
    const int fq   = lane >> 4;

    f32x4 acc[4][4];
    const f32x4 zero = {0.f, 0.f, 0.f, 0.f};
#pragma unroll
    for (int mi = 0; mi < 4; mi++)
#pragma unroll
        for (int ni = 0; ni < 4; ni++) acc[mi][ni] = zero;

    const float* Ap = A + (size_t)trow * 128 * K;
    const float* Bp = B + (size_t)tcol * 128 * K;
    const int sr = tid >> 1;
    const int sc = (tid & 1) * 16;
    for (int k0 = 0; k0 < K; k0 += 32) {
        const float* pa = Ap + (size_t)sr * K + k0 + sc;
        const float* pb = Bp + (size_t)sr * K + k0 + sc;
        float4 a0 = *(const float4*)(pa + 0);
        float4 a1 = *(const float4*)(pa + 4);
        float4 a2 = *(const float4*)(pa + 8);
        float4 a3 = *(const float4*)(pa + 12);
        float4 b0 = *(const float4*)(pb + 0);
        float4 b1 = *(const float4*)(pb + 4);
        float4 b2 = *(const float4*)(pb + 8);
        float4 b3 = *(const float4*)(pb + 12);
        __syncthreads();
        char* la = (char*)As + sr * 64 + sc * 2;
        char* lb = (char*)Bs + sr * 64 + sc * 2;
        *(uint4*)(la)      = pack8(a0, a1);
        *(uint4*)(la + 16) = pack8(a2, a3);
        *(uint4*)(lb)      = pack8(b0, b1);
        *(uint4*)(lb + 16) = pack8(b2, b3);
        __syncthreads();
        bf16x8 af[4], bfv2[4];
#pragma unroll
        for (int mi = 0; mi < 4; mi++)
            af[mi] = *(const bf16x8*)&As[(wr * 64 + mi * 16 + fr) * 32 + fq * 8];
#pragma unroll
        for (int ni = 0; ni < 4; ni++)
            bfv2[ni] = *(const bf16x8*)&Bs[(wc * 64 + ni * 16 + fr) * 32 + fq * 8];
#pragma unroll
        for (int mi = 0; mi < 4; mi++)
#pragma unroll
            for (int ni = 0; ni < 4; ni++)
                acc[mi][ni] = __builtin_amdgcn_mfma_f32_16x16x32_bf16(af[mi], bfv2[ni],
                                                                      acc[mi][ni], 0, 0, 0);
    }
    __syncthreads();

    const int rowb = trow * 128 + wr * 64;
    const int colb = tcol * 128 + wc * 64;
#pragma unroll
    for (int mi = 0; mi < 4; mi++) {
        const int r0 = rowb + mi * 16 + fq * 4;
#pragma unroll
        for (int ni = 0; ni < 4; ni++) {
            const int c = colb + ni * 16 + fr;
            const float bvv = bias[c];
            float* p = out + (size_t)r0 * 8192 + c;
            f32x4 v = acc[mi][ni];
            p[0 * 8192] = v[0] + bvv;
            p[1 * 8192] = v[1] + bvv;
            p[2 * 8192] = v[2] + bvv;
            p[3 * 8192] = v[3] + bvv;
        }
    }
}

extern "C" void kernel_launch(void* const* d_in, const int* in_sizes, int n_in,
                              void* d_out, int out_size, void* d_ws, size_t ws_size,
                              hipStream_t stream) {
    const float* x    = (const float*)d_in[0];   // [4096, 1024]
    const float* wgt  = (const float*)d_in[1];   // [8, 1024, 1024] == Wbig^T [8192,1024]
    const float* bias = (const float*)d_in[2];   // [8, 1024] == [8192]
    float* out = (float*)d_out;                  // [4096, 8192]

    const size_t NX = (size_t)4096 * 1024;
    const size_t NW = (size_t)8192 * 1024;

    if (ws_size >= (NX + NW) * sizeof(bf16)) {
        bf16* xb = (bf16*)d_ws;
        bf16* wb = xb + NX;
        LE_cvt2_kernel<<<2048, 256, 0, stream>>>(x, wgt, xb, (int)NX, (int)(NX + NW));
        LE_gemm8_kernel<<<512, 512, 0, stream>>>(xb, wb, bias, out);
    } else {
        LE_gemm_fb_kernel<<<2048, 256, 0, stream>>>(x, wgt, bias, out);
    }
}